// Round 7
// baseline (213.493 us; speedup 1.0000x reference)
//
#include <hip/hip_runtime.h>
#include <math.h>

#define VOCAB 50000
#define VPAD  50048      // padded vocab rows (zeroed) -> no guards in hot loop
#define EMB   100
#define KP    128        // hb row stride (shorts)
#define KP2   136        // ub/us row stride (shorts): 272 B, 16B-aligned
#define BATCH 2048
#define CTX   10

#define NVT   391        // 128-wide vocab tiles (391*128 = 50048)
#define BC    4          // batch chunks; block covers 512 b in 4 subtiles of 128
#define PROWS (2 * NVT)  // partial rows: (vy, v-half) = 782

typedef __attribute__((ext_vector_type(8))) short short8;
typedef __attribute__((ext_vector_type(4))) float f32x4;

__device__ __forceinline__ unsigned short f2bf(float x) {
    union { float f; unsigned u; } v; v.f = x;
    unsigned r = (v.u + 0x7FFFu + ((v.u >> 16) & 1u)) >> 16;  // RNE
    return (unsigned short)r;
}

// ---------------- dense pre-convert: emb_u fp32 [50000][100] -> bf16 ub[50048][136] ----------------
// ALL rows written; rows >= VOCAB and cols >= 100 are exact zeros -> pad scores are exactly 0,
// sigmoid contributes exactly 0.5 each (48 pads -> constant 24.0 removed in k_redfinal).
__global__ void k_cvt(const float* __restrict__ u, unsigned short* __restrict__ ub) {
    const int c = blockIdx.x * 256 + threadIdx.x;   // 17 x 16B chunks per row
    if (c >= VPAD * 17) return;
    const int row = c / 17;
    const int seg = c % 17;
    short8 o = (short8)(short)0;
    if (row < VOCAB) {
        if (seg < 12) {          // cols seg*8 .. +8 valid
            const float4* p = (const float4*)&u[row * EMB + seg * 8];
            const float4 a = p[0], b = p[1];
            o[0] = (short)f2bf(a.x); o[1] = (short)f2bf(a.y);
            o[2] = (short)f2bf(a.z); o[3] = (short)f2bf(a.w);
            o[4] = (short)f2bf(b.x); o[5] = (short)f2bf(b.y);
            o[6] = (short)f2bf(b.z); o[7] = (short)f2bf(b.w);
        } else if (seg == 12) {  // cols 96..99 valid, 100..103 zero
            const float4 a = *(const float4*)&u[row * EMB + 96];
            o[0] = (short)f2bf(a.x); o[1] = (short)f2bf(a.y);
            o[2] = (short)f2bf(a.z); o[3] = (short)f2bf(a.w);
        }
    }
    *(short8*)&ub[row * KP2 + seg * 8] = o;
}

// ---------------- h = mean of context embeddings; fp32 (pos term) + bf16 padded ----------------
__global__ void k_h(const int* __restrict__ x, const float* __restrict__ emb_v,
                    float* __restrict__ hf, unsigned short* __restrict__ hb,
                    float* __restrict__ out) {
    const int b = blockIdx.x;
    const int e = threadIdx.x;  // 0..127
    if (b == 0 && e == 0) out[0] = 0.0f;
    float s = 0.0f;
    if (e < EMB) {
#pragma unroll
        for (int c = 0; c < CTX; ++c) {
            const int idx = x[b * CTX + c];
            s += emb_v[idx * EMB + e];
        }
        s *= (1.0f / CTX);
        hf[b * EMB + e] = s;
    }
    hb[b * KP + e] = (e < EMB) ? f2bf(s) : (unsigned short)0;
}

// ---------------- fused bf16-MFMA GEMM + sigmoid row-sum (TLP-max) ----------------
// A = u (m=v), B = h (n=b). D: col(lane&15)=b, row(q*4+reg)=v.
// Registers minimized (af/bf streamed per-kc) so 4 waves/EU = 16 waves/CU fit;
// latency hidden by thread-level parallelism, not per-wave ILP.
__global__ __launch_bounds__(256, 4)
void k_neg(const unsigned short* __restrict__ hb, const unsigned short* __restrict__ ub,
           float* __restrict__ partial) {
    __shared__ unsigned short us[128 * KP2];   // 34816 B -> 4 blocks/CU

    const int t   = threadIdx.x;
    const int w   = t >> 6;          // wave 0..3
    const int L   = t & 63;
    const int c16 = L & 15;
    const int q   = L >> 4;
    const int wm  = (w & 1) * 64;    // wave v-offset within 128-tile
    const int wn  = (w >> 1) * 64;   // wave b-offset within 128-subtile
    const int vy  = blockIdx.y;
    const int v0  = vy * 128;

    // ---- stage u tile: flat contiguous copy, 2176 chunks of 16 B ----
    const unsigned short* src = ub + (size_t)v0 * KP2;
#pragma unroll
    for (int i = 0; i < 8; ++i)
        *(short8*)&us[(i * 256 + t) * 8] = *(const short8*)&src[(i * 256 + t) * 8];
    if (t < 128)
        *(short8*)&us[(2048 + t) * 8] = *(const short8*)&src[(2048 + t) * 8];
    __syncthreads();   // the only barrier

    const int    b0base = blockIdx.x * (BATCH / BC);
    const size_t hbase  = (size_t)(b0base + wn + c16) * KP + q * 8;
    const int    prow   = (2 * vy + (w & 1)) * BATCH + b0base + wn;

#pragma unroll 1
    for (int bt = 0; bt < 4; ++bt) {   // 4 subtiles of 128 b
        f32x4 acc[4][4];
#pragma unroll
        for (int mi = 0; mi < 4; ++mi)
#pragma unroll
            for (int ni = 0; ni < 4; ++ni) acc[mi][ni] = (f32x4)(0.0f);

#pragma unroll
        for (int kc = 0; kc < 4; ++kc) {
            short8 af[4], bf[4];
#pragma unroll
            for (int ni = 0; ni < 4; ++ni)
                bf[ni] = *(const short8*)&hb[hbase + (size_t)(bt * 128 + ni * 16) * KP + kc * 32];
#pragma unroll
            for (int mi = 0; mi < 4; ++mi)
                af[mi] = *(const short8*)&us[(wm + mi * 16 + c16) * KP2 + kc * 32 + q * 8];
#pragma unroll
            for (int mi = 0; mi < 4; ++mi)
#pragma unroll
                for (int ni = 0; ni < 4; ++ni)
                    acc[mi][ni] = __builtin_amdgcn_mfma_f32_16x16x32_bf16(
                        af[mi], bf[ni], acc[mi][ni], 0, 0, 0);
        }

        // ---- epilogue: sum_v sigmoid(-score); 4-way combine, no guards ----
        // sum 1/(1+ei) over pair = (2+ea+eb)/((1+ea)(1+eb)); (1+x)(1+y) = fma(x,y,1+x+y)
#pragma unroll
        for (int ni = 0; ni < 4; ++ni) {
            float p = 0.0f;
#pragma unroll
            for (int mi = 0; mi < 4; ++mi) {
                const float ea = __expf(acc[mi][ni][0]);
                const float eb = __expf(acc[mi][ni][1]);
                const float ec = __expf(acc[mi][ni][2]);
                const float ed = __expf(acc[mi][ni][3]);
                const float n1 = 2.0f + ea + eb;
                const float d1 = fmaf(ea, eb, n1 - 1.0f);
                const float n2 = 2.0f + ec + ed;
                const float d2 = fmaf(ec, ed, n2 - 1.0f);
                const float N  = fmaf(n1, d2, n2 * d1);
                p = fmaf(N, __builtin_amdgcn_rcpf(d1 * d2), p);
            }
            p += __shfl_down(p, 32);   // fold q
            p += __shfl_down(p, 16);
            if (L < 16)
                partial[prow + bt * 128 + ni * 16 + L] = p;
        }
    }
}

// ---------------- reduce partial rows + pos term + mean ----------------
// 32 blocks x 1024 threads: 64 b-lanes x 16 row-waves, coalesced across b.
__global__ void k_redfinal(const int* __restrict__ y, const float* __restrict__ hf,
                           const float* __restrict__ u, const float* __restrict__ partial,
                           float* __restrict__ out) {
    const int t    = threadIdx.x;
    const int lane = t & 63;
    const int w    = t >> 6;          // 0..15
    const int b    = blockIdx.x * 64 + lane;
    float s = 0.0f;
    for (int r = w; r < PROWS; r += 16)
        s += partial[r * BATCH + b];  // coalesced across 64 lanes
    __shared__ float red[16][64];
    red[w][lane] = s;
    __syncthreads();
    if (w == 0) {
        float ns = -24.0f;            // remove the 48 zero-pad rows' exact 0.5 each
#pragma unroll
        for (int i = 0; i < 16; ++i) ns += red[i][lane];

        const int yi = y[b];
        const float4* hp = (const float4*)&hf[b * EMB];
        const float4* up = (const float4*)&u[yi * EMB];
        float dot = 0.0f;
#pragma unroll
        for (int qq = 0; qq < EMB / 4; ++qq) {
            const float4 a = hp[qq];
            const float4 c = up[qq];
            dot += a.x * c.x + a.y * c.y + a.z * c.z + a.w * c.w;
        }
        const float pos = fmaxf(-dot, 0.0f) + log1pf(__expf(-fabsf(dot)));  // softplus(-dot)
        float val = pos + logf(ns);
#pragma unroll
        for (int off = 32; off; off >>= 1) val += __shfl_down(val, off, 64);
        if (lane == 0) atomicAdd(out, val * (1.0f / BATCH));
    }
}

extern "C" void kernel_launch(void* const* d_in, const int* in_sizes, int n_in,
                              void* d_out, int out_size, void* d_ws, size_t ws_size,
                              hipStream_t stream) {
    const int*   x     = (const int*)d_in[0];
    const int*   y     = (const int*)d_in[1];
    const float* emb_v = (const float*)d_in[2];
    const float* emb_u = (const float*)d_in[3];
    float* out = (float*)d_out;

    // workspace carve (~21.4 MB), all sections 16B-aligned
    float*          hf      = (float*)d_ws;                          // 2048*100 fp32
    float*          partial = hf + BATCH * EMB;                      // 782*2048 fp32
    unsigned short* hb      = (unsigned short*)(partial + PROWS * BATCH);  // 2048*128 bf16
    unsigned short* ub      = hb + BATCH * KP;                       // 50048*136 bf16

    k_cvt     <<<dim3((VPAD * 17 + 255) / 256), dim3(256), 0, stream>>>(emb_u, ub);
    k_h       <<<dim3(BATCH), dim3(128), 0, stream>>>(x, emb_v, hf, hb, out);
    k_neg     <<<dim3(BC, NVT), dim3(256), 0, stream>>>(hb, ub, partial);
    k_redfinal<<<dim3(BATCH / 64), dim3(1024), 0, stream>>>(y, hf, emb_u, partial, out);
}

// Round 8
// 144.124 us; speedup vs baseline: 1.4813x; 1.4813x over previous
//
#include <hip/hip_runtime.h>
#include <math.h>

#define VOCAB 50000
#define VPAD  50048      // padded vocab rows (zeroed): no guards in hot loop
#define EMB   100
#define BATCH 2048
#define CTX   10

#define NVT   391        // 128-wide vocab tiles (391*128 = 50048)
#define BC    4          // batch chunks; block covers 512 b in 8 subtiles of 64
#define PROWS (2 * NVT)  // partial rows: (vy, v-half) = 782

// Fragment-order layouts (lane L = q*16 + c16 holds k = kc*32 + q*8 + j):
//   ubf[tile][ (mg*4+kc)*512 + L*8 + j ]   tile=v>>7, mg=(v>>4)&7, c16=v&15   (16384 sh/tile)
//   hbf[ (b>>4)*2048 + kc*512 + L*8 + j ]  c16=b&15                            (512 KB total)
// -> every A/B fragment load is 64 lanes x 16 B CONTIGUOUS (1 KB).

typedef __attribute__((ext_vector_type(8))) short short8;
typedef __attribute__((ext_vector_type(4))) float f32x4;

__device__ __forceinline__ unsigned short f2bf(float x) {
    union { float f; unsigned u; } v; v.f = x;
    unsigned r = (v.u + 0x7FFFu + ((v.u >> 16) & 1u)) >> 16;  // RNE
    return (unsigned short)r;
}

// ---------------- emb_u fp32 [50000][100] -> bf16 fragment-order ubf [391][16384] ----------------
// Pad rows (>=VOCAB) and pad cols (>=100) exact zero -> pad score 0 -> sigmoid 0.5 each,
// removed as a constant in k_redfinal.
__global__ void k_cvt(const float* __restrict__ u, unsigned short* __restrict__ ubf) {
    const int c = blockIdx.x * 256 + threadIdx.x;   // 16 fragment-chunks per row
    const int row = c >> 4;
    const int fc  = c & 15;
    const int kc  = fc >> 2;
    const int q   = fc & 3;
    const int e   = kc * 32 + q * 8;
    short8 o = (short8)(short)0;
    if (row < VOCAB) {
        if (e + 8 <= EMB) {
            const float4 a = *(const float4*)&u[row * EMB + e];
            const float4 b = *(const float4*)&u[row * EMB + e + 4];
            o[0] = (short)f2bf(a.x); o[1] = (short)f2bf(a.y);
            o[2] = (short)f2bf(a.z); o[3] = (short)f2bf(a.w);
            o[4] = (short)f2bf(b.x); o[5] = (short)f2bf(b.y);
            o[6] = (short)f2bf(b.z); o[7] = (short)f2bf(b.w);
        } else if (e < EMB) {   // e == 96: cols 96..99 valid
            const float4 a = *(const float4*)&u[row * EMB + e];
            o[0] = (short)f2bf(a.x); o[1] = (short)f2bf(a.y);
            o[2] = (short)f2bf(a.z); o[3] = (short)f2bf(a.w);
        }
    }
    const int tile = row >> 7, mg = (row >> 4) & 7, c16 = row & 15;
    *(short8*)&ubf[(size_t)tile * 16384 + ((mg * 4 + kc) * 64 + q * 16 + c16) * 8] = o;
}

// ---------------- h = mean of context embeddings; fp32 (pos term) + bf16 fragment-order ----------------
__global__ void k_h(const int* __restrict__ x, const float* __restrict__ emb_v,
                    float* __restrict__ hf, unsigned short* __restrict__ hbf,
                    float* __restrict__ out) {
    const int b = blockIdx.x;
    const int e = threadIdx.x;  // 0..127
    if (b == 0 && e == 0) out[0] = 0.0f;
    float s = 0.0f;
    if (e < EMB) {
#pragma unroll
        for (int c = 0; c < CTX; ++c) {
            const int idx = x[b * CTX + c];
            s += emb_v[idx * EMB + e];
        }
        s *= (1.0f / CTX);
        hf[b * EMB + e] = s;
    }
    const int kc = e >> 5, q = (e >> 3) & 3, j = e & 7;
    hbf[(b >> 4) * 2048 + (kc * 64 + q * 16 + (b & 15)) * 8 + j] =
        (e < EMB) ? f2bf(s) : (unsigned short)0;
}

// ---------------- fused bf16-MFMA GEMM + sigmoid row-sum ----------------
// A = u (m=v), B = h (n=b). D: col(lane&15)=b, row(q*4+reg)=v.
// Wave tile 64v x 32b -> acc = 32 AGPRs; af/bf streamed per kc (fragment-order,
// fully coalesced / conflict-free). 4 blocks/CU, 16 waves/CU. No loop barriers.
__global__ __launch_bounds__(256, 4)
void k_neg(const unsigned short* __restrict__ hbf, const unsigned short* __restrict__ ubf,
           float* __restrict__ partial) {
    __shared__ unsigned short us[16384];   // 32 KB, flat fragment-order tile

    const int t   = threadIdx.x;
    const int w   = t >> 6;          // wave 0..3
    const int L   = t & 63;
    const int wvh = w & 1;           // v half (mg 0..3 or 4..7)
    const int wbh = w >> 1;          // b half within 64-b subtile
    const int vy  = blockIdx.y;

    // ---- stage u tile: flat contiguous 32 KB copy (2048 x 16 B) ----
    const unsigned short* src = ubf + (size_t)vy * 16384;
#pragma unroll
    for (int i = 0; i < 8; ++i)
        *(short8*)&us[(i * 256 + t) * 8] = *(const short8*)&src[(i * 256 + t) * 8];
    __syncthreads();   // the only barrier

    const int b0base = blockIdx.x * (BATCH / BC);   // 512
    const int prow   = (2 * vy + wvh) * BATCH;

#pragma unroll 1
    for (int bt = 0; bt < 8; ++bt) {   // 8 subtiles of 64 b
        const int Bg0 = (b0base + bt * 64) >> 4;    // first 16-b group

        f32x4 acc[4][2];
#pragma unroll
        for (int mi = 0; mi < 4; ++mi)
#pragma unroll
            for (int ni = 0; ni < 2; ++ni) acc[mi][ni] = (f32x4)(0.0f);

#pragma unroll
        for (int kc = 0; kc < 4; ++kc) {
            short8 af[4], bf[2];
#pragma unroll
            for (int ni = 0; ni < 2; ++ni)
                bf[ni] = *(const short8*)&hbf[(size_t)(Bg0 + wbh * 2 + ni) * 2048 + (kc * 64 + L) * 8];
#pragma unroll
            for (int mi = 0; mi < 4; ++mi)
                af[mi] = *(const short8*)&us[(((wvh * 4 + mi) * 4 + kc) * 64 + L) * 8];
#pragma unroll
            for (int mi = 0; mi < 4; ++mi)
#pragma unroll
                for (int ni = 0; ni < 2; ++ni)
                    acc[mi][ni] = __builtin_amdgcn_mfma_f32_16x16x32_bf16(
                        af[mi], bf[ni], acc[mi][ni], 0, 0, 0);
        }

        // ---- epilogue: sum_v sigmoid(-score); 4-way combine, no guards ----
#pragma unroll
        for (int ni = 0; ni < 2; ++ni) {
            float p = 0.0f;
#pragma unroll
            for (int mi = 0; mi < 4; ++mi) {
                const float ea = __expf(acc[mi][ni][0]);
                const float eb = __expf(acc[mi][ni][1]);
                const float ec = __expf(acc[mi][ni][2]);
                const float ed = __expf(acc[mi][ni][3]);
                const float n1 = 2.0f + ea + eb;
                const float d1 = fmaf(ea, eb, n1 - 1.0f);
                const float n2 = 2.0f + ec + ed;
                const float d2 = fmaf(ec, ed, n2 - 1.0f);
                const float N  = fmaf(n1, d2, n2 * d1);
                p = fmaf(N, __builtin_amdgcn_rcpf(d1 * d2), p);
            }
            p += __shfl_down(p, 32);   // fold q
            p += __shfl_down(p, 16);
            if (L < 16)
                partial[prow + b0base + bt * 64 + wbh * 32 + ni * 16 + L] = p;
        }
    }
}

// ---------------- reduce partial rows + pos term + mean ----------------
// 32 blocks x 1024 threads: 64 b-lanes x 16 row-waves, coalesced across b.
__global__ void k_redfinal(const int* __restrict__ y, const float* __restrict__ hf,
                           const float* __restrict__ u, const float* __restrict__ partial,
                           float* __restrict__ out) {
    const int t    = threadIdx.x;
    const int lane = t & 63;
    const int w    = t >> 6;          // 0..15
    const int b    = blockIdx.x * 64 + lane;
    float s = 0.0f;
    for (int r = w; r < PROWS; r += 16)
        s += partial[r * BATCH + b];  // coalesced across 64 lanes
    __shared__ float red[16][64];
    red[w][lane] = s;
    __syncthreads();
    if (w == 0) {
        float ns = -(float)(VPAD - VOCAB) * 0.5f;   // remove zero-pad rows (exact 0.5 each)
#pragma unroll
        for (int i = 0; i < 16; ++i) ns += red[i][lane];

        const int yi = y[b];
        const float4* hp = (const float4*)&hf[b * EMB];
        const float4* up = (const float4*)&u[yi * EMB];
        float dot = 0.0f;
#pragma unroll
        for (int qq = 0; qq < EMB / 4; ++qq) {
            const float4 a = hp[qq];
            const float4 c = up[qq];
            dot += a.x * c.x + a.y * c.y + a.z * c.z + a.w * c.w;
        }
        const float pos = fmaxf(-dot, 0.0f) + log1pf(__expf(-fabsf(dot)));  // softplus(-dot)
        float val = pos + logf(ns);
#pragma unroll
        for (int off = 32; off; off >>= 1) val += __shfl_down(val, off, 64);
        if (lane == 0) atomicAdd(out, val * (1.0f / BATCH));
    }
}

extern "C" void kernel_launch(void* const* d_in, const int* in_sizes, int n_in,
                              void* d_out, int out_size, void* d_ws, size_t ws_size,
                              hipStream_t stream) {
    const int*   x     = (const int*)d_in[0];
    const int*   y     = (const int*)d_in[1];
    const float* emb_v = (const float*)d_in[2];
    const float* emb_u = (const float*)d_in[3];
    float* out = (float*)d_out;

    // workspace carve (~20.3 MB), all sections 16B-aligned
    float*          hf      = (float*)d_ws;                          // 2048*100 fp32
    float*          partial = hf + BATCH * EMB;                      // 782*2048 fp32
    unsigned short* hbf     = (unsigned short*)(partial + PROWS * BATCH);  // 2048*128 bf16
    unsigned short* ubf     = hbf + BATCH * 128;                     // 391*16384 bf16

    k_cvt     <<<dim3(VPAD * 16 / 256), dim3(256), 0, stream>>>(emb_u, ubf);
    k_h       <<<dim3(BATCH), dim3(128), 0, stream>>>(x, emb_v, hf, hbf, out);
    k_neg     <<<dim3(BC, NVT), dim3(256), 0, stream>>>(hbf, ubf, partial);
    k_redfinal<<<dim3(BATCH / 64), dim3(1024), 0, stream>>>(y, hf, emb_u, partial, out);
}

// Round 9
// 142.987 us; speedup vs baseline: 1.4931x; 1.0080x over previous
//
#include <hip/hip_runtime.h>
#include <math.h>

#define VOCAB 50000
#define VPAD  50048      // padded vocab rows (zeroed): no guards in hot loop
#define EMB   100
#define BATCH 2048
#define CTX   10

#define NVT   391        // 128-wide vocab tiles (391*128 = 50048)
#define BC    4          // batch chunks; block covers 512 b in 8 subtiles of 64
#define PROWS (2 * NVT)  // partial rows: (vy, v-half) = 782

#define CVTB  (VPAD / 16)   // 3128 cvt blocks in k_prep
#define HB    1024          // h blocks in k_prep (2 b each)

// Fragment-order layouts (lane L = q*16 + c16 holds k = kc*32 + q*8 + j):
//   ubf[tile][ (mg*4+kc)*512 + L*8 + j ]   tile=v>>7, mg=(v>>4)&7, c16=v&15
//   hbf[ (b>>4)*2048 + kc*512 + L*8 + j ]  c16=b&15
// -> every A/B fragment load is 64 lanes x 16 B CONTIGUOUS (1 KB).

typedef __attribute__((ext_vector_type(8))) short short8;
typedef __attribute__((ext_vector_type(4))) float f32x4;

__device__ __forceinline__ unsigned short f2bf(float x) {
    union { float f; unsigned u; } v; v.f = x;
    unsigned r = (v.u + 0x7FFFu + ((v.u >> 16) & 1u)) >> 16;  // RNE
    return (unsigned short)r;
}

// ---------------- prep: emb_u -> fragment-order ubf (coalesced writes) + h ----------------
__global__ __launch_bounds__(256)
void k_prep(const float* __restrict__ u, unsigned short* __restrict__ ubf,
            const int* __restrict__ x, const float* __restrict__ emb_v,
            float* __restrict__ hf, unsigned short* __restrict__ hbf,
            float* __restrict__ out) {
    const int blk = blockIdx.x;
    const int t   = threadIdx.x;
    if (blk < CVTB) {
        // ---- cvt: 16 rows (one mg group); write offset == t*16B -> contiguous 4 KB ----
        const int r0  = blk * 16;
        const int c16 = t & 15;        // row within group
        const int fc  = t >> 4;        // fragment chunk: kc*4 + q
        const int kc  = fc >> 2, q = fc & 3;
        const int row = r0 + c16;
        const int e   = kc * 32 + q * 8;
        short8 o = (short8)(short)0;
        if (row < VOCAB) {
            if (e + 8 <= EMB) {
                const float4 a = *(const float4*)&u[row * EMB + e];
                const float4 b = *(const float4*)&u[row * EMB + e + 4];
                o[0] = (short)f2bf(a.x); o[1] = (short)f2bf(a.y);
                o[2] = (short)f2bf(a.z); o[3] = (short)f2bf(a.w);
                o[4] = (short)f2bf(b.x); o[5] = (short)f2bf(b.y);
                o[6] = (short)f2bf(b.z); o[7] = (short)f2bf(b.w);
            } else if (e < EMB) {      // e == 96: cols 96..99 valid
                const float4 a = *(const float4*)&u[row * EMB + e];
                o[0] = (short)f2bf(a.x); o[1] = (short)f2bf(a.y);
                o[2] = (short)f2bf(a.z); o[3] = (short)f2bf(a.w);
            }
        }
        const int tile = r0 >> 7, mg = (r0 >> 4) & 7;
        *(short8*)&ubf[(size_t)tile * 16384 + (size_t)mg * 2048 + t * 8] = o;
    } else {
        // ---- h: 2 b per block ----
        const int b = (blk - CVTB) * 2 + (t >> 7);
        const int e = t & 127;
        if (blk == CVTB && t == 0) out[0] = 0.0f;
        float s = 0.0f;
        if (e < EMB) {
#pragma unroll
            for (int c = 0; c < CTX; ++c) {
                const int idx = x[b * CTX + c];
                s += emb_v[idx * EMB + e];
            }
            s *= (1.0f / CTX);
            hf[b * EMB + e] = s;
        }
        const int kc = e >> 5, q = (e >> 3) & 3, j = e & 7;
        hbf[(b >> 4) * 2048 + (kc * 64 + q * 16 + (b & 15)) * 8 + j] =
            (e < EMB) ? f2bf(s) : (unsigned short)0;
    }
}

// ---------------- fused bf16-MFMA GEMM + sigmoid row-sum ----------------
// A = u (m=v), B = h (n=b). D: col(lane&15)=b, row(q*4+reg)=v.
// Wave tile 64v x 32b (acc = 32 AGPR). af for kc 0..1 cached in 32 VGPRs (halves
// LDS read traffic); kc 2..3 streamed from LDS. bf streamed from L2-hot hbf.
// 4 blocks/CU; no loop barriers; no atomics (wave-disjoint partial rows).
__global__ __launch_bounds__(256, 4)
void k_neg(const unsigned short* __restrict__ hbf, const unsigned short* __restrict__ ubf,
           float* __restrict__ partial) {
    __shared__ unsigned short us[16384];   // 32 KB, flat fragment-order tile

    const int t   = threadIdx.x;
    const int w   = t >> 6;          // wave 0..3
    const int L   = t & 63;
    const int wvh = w & 1;           // v half (mg 0..3 or 4..7)
    const int wbh = w >> 1;          // b half within 64-b subtile
    const int vy  = blockIdx.y;

    // ---- stage u tile: flat contiguous 32 KB copy ----
    const unsigned short* src = ubf + (size_t)vy * 16384;
#pragma unroll
    for (int i = 0; i < 8; ++i)
        *(short8*)&us[(i * 256 + t) * 8] = *(const short8*)&src[(i * 256 + t) * 8];
    __syncthreads();   // the only barrier

    // ---- cache af for kc 0..1 (32 VGPRs) ----
    short8 af01[2][4];
#pragma unroll
    for (int kc = 0; kc < 2; ++kc)
#pragma unroll
        for (int mi = 0; mi < 4; ++mi)
            af01[kc][mi] = *(const short8*)&us[(((wvh * 4 + mi) * 4 + kc) * 64 + L) * 8];

    const int b0base = blockIdx.x * (BATCH / BC);   // 512
    const int prow   = (2 * vy + wvh) * BATCH;

#pragma unroll 1
    for (int bt = 0; bt < 8; ++bt) {   // 8 subtiles of 64 b
        const int Bg0 = (b0base + bt * 64) >> 4;    // first 16-b group

        f32x4 acc[4][2];
#pragma unroll
        for (int mi = 0; mi < 4; ++mi)
#pragma unroll
            for (int ni = 0; ni < 2; ++ni) acc[mi][ni] = (f32x4)(0.0f);

#pragma unroll
        for (int kc = 0; kc < 4; ++kc) {
            short8 bf[2];
#pragma unroll
            for (int ni = 0; ni < 2; ++ni)
                bf[ni] = *(const short8*)&hbf[(size_t)(Bg0 + wbh * 2 + ni) * 2048 + (kc * 64 + L) * 8];
#pragma unroll
            for (int mi = 0; mi < 4; ++mi) {
                const short8 af = (kc < 2)
                    ? af01[kc][mi]
                    : *(const short8*)&us[(((wvh * 4 + mi) * 4 + kc) * 64 + L) * 8];
#pragma unroll
                for (int ni = 0; ni < 2; ++ni)
                    acc[mi][ni] = __builtin_amdgcn_mfma_f32_16x16x32_bf16(
                        af, bf[ni], acc[mi][ni], 0, 0, 0);
            }
        }

        // ---- epilogue: sum_v sigmoid(-score); 4-way combine, no guards ----
#pragma unroll
        for (int ni = 0; ni < 2; ++ni) {
            float p = 0.0f;
#pragma unroll
            for (int mi = 0; mi < 4; ++mi) {
                const float ea = __expf(acc[mi][ni][0]);
                const float eb = __expf(acc[mi][ni][1]);
                const float ec = __expf(acc[mi][ni][2]);
                const float ed = __expf(acc[mi][ni][3]);
                const float n1 = 2.0f + ea + eb;
                const float d1 = fmaf(ea, eb, n1 - 1.0f);
                const float n2 = 2.0f + ec + ed;
                const float d2 = fmaf(ec, ed, n2 - 1.0f);
                const float N  = fmaf(n1, d2, n2 * d1);
                p = fmaf(N, __builtin_amdgcn_rcpf(d1 * d2), p);
            }
            p += __shfl_down(p, 32);   // fold q
            p += __shfl_down(p, 16);
            if (L < 16)
                partial[prow + b0base + bt * 64 + wbh * 32 + ni * 16 + L] = p;
        }
    }
}

// ---------------- reduce partial rows + pos term + mean ----------------
// 32 blocks x 1024 threads: 64 b-lanes x 16 row-waves, coalesced across b.
__global__ void k_redfinal(const int* __restrict__ y, const float* __restrict__ hf,
                           const float* __restrict__ u, const float* __restrict__ partial,
                           float* __restrict__ out) {
    const int t    = threadIdx.x;
    const int lane = t & 63;
    const int w    = t >> 6;          // 0..15
    const int b    = blockIdx.x * 64 + lane;
    float s = 0.0f;
    for (int r = w; r < PROWS; r += 16)
        s += partial[r * BATCH + b];  // coalesced across 64 lanes
    __shared__ float red[16][64];
    red[w][lane] = s;
    __syncthreads();
    if (w == 0) {
        float ns = -(float)(VPAD - VOCAB) * 0.5f;   // remove zero-pad rows (exact 0.5 each)
#pragma unroll
        for (int i = 0; i < 16; ++i) ns += red[i][lane];

        const int yi = y[b];
        const float4* hp = (const float4*)&hf[b * EMB];
        const float4* up = (const float4*)&u[yi * EMB];
        float dot = 0.0f;
#pragma unroll
        for (int qq = 0; qq < EMB / 4; ++qq) {
            const float4 a = hp[qq];
            const float4 c = up[qq];
            dot += a.x * c.x + a.y * c.y + a.z * c.z + a.w * c.w;
        }
        const float pos = fmaxf(-dot, 0.0f) + log1pf(__expf(-fabsf(dot)));  // softplus(-dot)
        float val = pos + logf(ns);
#pragma unroll
        for (int off = 32; off; off >>= 1) val += __shfl_down(val, off, 64);
        if (lane == 0) atomicAdd(out, val * (1.0f / BATCH));
    }
}

extern "C" void kernel_launch(void* const* d_in, const int* in_sizes, int n_in,
                              void* d_out, int out_size, void* d_ws, size_t ws_size,
                              hipStream_t stream) {
    const int*   x     = (const int*)d_in[0];
    const int*   y     = (const int*)d_in[1];
    const float* emb_v = (const float*)d_in[2];
    const float* emb_u = (const float*)d_in[3];
    float* out = (float*)d_out;

    // workspace carve (~20.3 MB), all sections 16B-aligned
    float*          hf      = (float*)d_ws;                          // 2048*100 fp32
    float*          partial = hf + BATCH * EMB;                      // 782*2048 fp32
    unsigned short* hbf     = (unsigned short*)(partial + PROWS * BATCH);  // 2048*128 bf16
    unsigned short* ubf     = hbf + BATCH * 128;                     // 391*16384 bf16

    k_prep    <<<dim3(CVTB + HB), dim3(256), 0, stream>>>(emb_u, ubf, x, emb_v, hf, hbf, out);
    k_neg     <<<dim3(BC, NVT), dim3(256), 0, stream>>>(hbf, ubf, partial);
    k_redfinal<<<dim3(BATCH / 64), dim3(1024), 0, stream>>>(y, hf, emb_u, partial, out);
}

// Round 10
// 131.176 us; speedup vs baseline: 1.6275x; 1.0900x over previous
//
#include <hip/hip_runtime.h>
#include <math.h>

#define VOCAB 50000
#define VPAD  50048      // padded vocab rows (zeroed): no guards in hot loop
#define EMB   100
#define BATCH 2048
#define CTX   10

#define NVT   391        // 128-wide vocab tiles (391*128 = 50048)
#define BC    8          // batch chunks; block covers 256 b in 4 subtiles of 64
#define PROWS (2 * NVT)  // partial rows: (vy, v-half) = 782
#define NMG   (VPAD / 16)   // 3128 16-row fragment groups
#define CVTB  (NMG / 4)     // 782 cvt blocks (4 mg each)
#define HBLK  (BATCH / 2)   // 1024 h blocks (2 b each)

// fp8 fragment order (K=128, lane L = q*16 + c16 holds k = q*32 + j, j=0..31):
//   ub8[(mg*64 + L)*32 + j]   mg = v>>4, c16 = v&15      (2 KB per 16 v-rows)
//   hb8[(bg*64 + L)*32 + j]   bg = b>>4, c16 = b&15      (2 KB per 16 b)
// -> every A/B fragment load is 64 lanes x 32 B CONTIGUOUS (2 KB).

typedef __attribute__((ext_vector_type(8))) int   i32x8;
typedef __attribute__((ext_vector_type(4))) float f32x4;

// ---------------- prep: emb_u -> fp8 fragment-order ub8 + h (fp32 + fp8 frag-order) ----------------
__global__ __launch_bounds__(256)
void k_prep(const float* __restrict__ u, unsigned char* __restrict__ ub8,
            const int* __restrict__ x, const float* __restrict__ emb_v,
            float* __restrict__ hf, unsigned char* __restrict__ hb8,
            float* __restrict__ out) {
    const int blk = blockIdx.x;
    const int t   = threadIdx.x;
    if (blk < CVTB) {
        // ---- cvt: 4 mg groups per block; thread t writes 32 contiguous bytes ----
        const int mgid = blk * 4 + (t >> 6);
        const int L    = t & 63;
        const int c16  = L & 15;
        const int q    = L >> 4;
        const int row  = mgid * 16 + c16;
        const int e0   = q * 32;
        i32x8 o = (i32x8)0;
        if (row < VOCAB) {
            if (q < 3) {             // cols e0..e0+31 all valid
                const float4* p = (const float4*)&u[row * EMB + e0];
#pragma unroll
                for (int j = 0; j < 8; ++j) {
                    const float4 v = p[j];
                    int wd = __builtin_amdgcn_cvt_pk_fp8_f32(v.x, v.y, 0, false);
                    wd     = __builtin_amdgcn_cvt_pk_fp8_f32(v.z, v.w, wd, true);
                    o[j] = wd;
                }
            } else {                 // q==3: cols 96..99 valid, 100..127 zero
                const float4 v = *(const float4*)&u[row * EMB + 96];
                int wd = __builtin_amdgcn_cvt_pk_fp8_f32(v.x, v.y, 0, false);
                wd     = __builtin_amdgcn_cvt_pk_fp8_f32(v.z, v.w, wd, true);
                o[0] = wd;
            }
        }
        *(i32x8*)&ub8[((size_t)mgid * 64 + L) * 32] = o;   // coalesced: offset == t*32
    } else {
        // ---- h: 2 b per block ----
        const int b = (blk - CVTB) * 2 + (t >> 7);
        const int e = t & 127;
        if (blk == CVTB && t == 0) out[0] = 0.0f;
        float s = 0.0f;
        if (e < EMB) {
#pragma unroll
            for (int c = 0; c < CTX; ++c) {
                const int idx = x[b * CTX + c];
                s += emb_v[idx * EMB + e];
            }
            s *= (1.0f / CTX);
            hf[b * EMB + e] = s;
        }
        const unsigned char f8 =
            (unsigned char)(__builtin_amdgcn_cvt_pk_fp8_f32(s, 0.0f, 0, false) & 0xFF);
        hb8[((b >> 4) * 64 + (e >> 5) * 16 + (b & 15)) * 32 + (e & 31)] = f8;
    }
}

// ---------------- fused MX-fp8 MFMA GEMM (K=128 per instr) + sigmoid row-sum ----------------
// A = u (m=v), B = h (n=b). D: col(lane&15)=b, row(q*4+reg)=v (shape-determined).
// Unit E8M0 scales (0x7F = 2^0). A-frags cached in 32 VGPRs; NO LDS, NO barriers,
// NO atomics. 4 waves/EU.
__global__ __launch_bounds__(256, 4)
void k_neg(const unsigned char* __restrict__ hb8, const unsigned char* __restrict__ ub8,
           float* __restrict__ partial) {
    const int t   = threadIdx.x;
    const int w   = t >> 6;          // wave 0..3
    const int L   = t & 63;
    const int wvh = w & 1;           // v half: mg 0..3 or 4..7 of the 128-v tile
    const int wbh = w >> 1;          // b half within 64-b subtile
    const int vy  = blockIdx.y;

    // ---- A fragments: 4 x 32 B/lane, loaded once, reused all subtiles ----
    i32x8 af[4];
#pragma unroll
    for (int mi = 0; mi < 4; ++mi)
        af[mi] = *(const i32x8*)&ub8[(((size_t)vy * 8 + wvh * 4 + mi) * 64 + L) * 32];

    const int b0base = blockIdx.x * (BATCH / BC);   // 256 b per block
    const int prow   = (2 * vy + wvh) * BATCH;

#pragma unroll 1
    for (int bt = 0; bt < (BATCH / BC) / 64; ++bt) {   // 4 subtiles of 64 b
        const int b0  = b0base + bt * 64;
        const int Bg0 = b0 >> 4;

        i32x8 bf[2];
#pragma unroll
        for (int ni = 0; ni < 2; ++ni)
            bf[ni] = *(const i32x8*)&hb8[((size_t)(Bg0 + wbh * 2 + ni) * 64 + L) * 32];

        f32x4 acc[4][2];
#pragma unroll
        for (int mi = 0; mi < 4; ++mi)
#pragma unroll
            for (int ni = 0; ni < 2; ++ni) acc[mi][ni] = (f32x4)(0.0f);

#pragma unroll
        for (int mi = 0; mi < 4; ++mi)
#pragma unroll
            for (int ni = 0; ni < 2; ++ni)
                acc[mi][ni] = __builtin_amdgcn_mfma_scale_f32_16x16x128_f8f6f4(
                    af[mi], bf[ni], acc[mi][ni],
                    0, 0,                 // cbsz=fp8(e4m3), blgp=fp8(e4m3)
                    0, 0x7F7F7F7F,        // scale_a sel/byte: 2^0
                    0, 0x7F7F7F7F);       // scale_b sel/byte: 2^0

        // ---- epilogue: sum_v sigmoid(-score); 4-way combine, no guards ----
#pragma unroll
        for (int ni = 0; ni < 2; ++ni) {
            float p = 0.0f;
#pragma unroll
            for (int mi = 0; mi < 4; ++mi) {
                const float ea = __expf(acc[mi][ni][0]);
                const float eb = __expf(acc[mi][ni][1]);
                const float ec = __expf(acc[mi][ni][2]);
                const float ed = __expf(acc[mi][ni][3]);
                const float n1 = 2.0f + ea + eb;
                const float d1 = fmaf(ea, eb, n1 - 1.0f);
                const float n2 = 2.0f + ec + ed;
                const float d2 = fmaf(ec, ed, n2 - 1.0f);
                const float N  = fmaf(n1, d2, n2 * d1);
                p = fmaf(N, __builtin_amdgcn_rcpf(d1 * d2), p);
            }
            p += __shfl_down(p, 32);   // fold q
            p += __shfl_down(p, 16);
            if (L < 16)
                partial[prow + b0 + wbh * 32 + ni * 16 + L] = p;
        }
    }
}

// ---------------- reduce partial rows + pos term + mean ----------------
__global__ void k_redfinal(const int* __restrict__ y, const float* __restrict__ hf,
                           const float* __restrict__ u, const float* __restrict__ partial,
                           float* __restrict__ out) {
    const int t    = threadIdx.x;
    const int lane = t & 63;
    const int w    = t >> 6;          // 0..15
    const int b    = blockIdx.x * 64 + lane;
    float s = 0.0f;
    for (int r = w; r < PROWS; r += 16)
        s += partial[r * BATCH + b];  // coalesced across 64 lanes
    __shared__ float red[16][64];
    red[w][lane] = s;
    __syncthreads();
    if (w == 0) {
        float ns = -(float)(VPAD - VOCAB) * 0.5f;   // remove zero-pad rows (exact 0.5 each)
#pragma unroll
        for (int i = 0; i < 16; ++i) ns += red[i][lane];

        const int yi = y[b];
        const float4* hp = (const float4*)&hf[b * EMB];
        const float4* up = (const float4*)&u[yi * EMB];
        float dot = 0.0f;
#pragma unroll
        for (int qq = 0; qq < EMB / 4; ++qq) {
            const float4 a = hp[qq];
            const float4 c = up[qq];
            dot += a.x * c.x + a.y * c.y + a.z * c.z + a.w * c.w;
        }
        const float pos = fmaxf(-dot, 0.0f) + log1pf(__expf(-fabsf(dot)));  // softplus(-dot)
        float val = pos + logf(ns);
#pragma unroll
        for (int off = 32; off; off >>= 1) val += __shfl_down(val, off, 64);
        if (lane == 0) atomicAdd(out, val * (1.0f / BATCH));
    }
}

extern "C" void kernel_launch(void* const* d_in, const int* in_sizes, int n_in,
                              void* d_out, int out_size, void* d_ws, size_t ws_size,
                              hipStream_t stream) {
    const int*   x     = (const int*)d_in[0];
    const int*   y     = (const int*)d_in[1];
    const float* emb_v = (const float*)d_in[2];
    const float* emb_u = (const float*)d_in[3];
    float* out = (float*)d_out;

    // workspace carve (~14 MB), 32B-aligned sections
    float*         hf      = (float*)d_ws;                            // 2048*100 fp32 (819200 B)
    float*         partial = hf + BATCH * EMB;                        // 782*2048 fp32 (6406144 B)
    unsigned char* hb8     = (unsigned char*)(partial + PROWS * BATCH);  // 128*2048 B
    unsigned char* ub8     = hb8 + (size_t)(BATCH / 16) * 2048;       // 3128*2048 B

    k_prep    <<<dim3(CVTB + HBLK), dim3(256), 0, stream>>>(emb_u, ub8, x, emb_v, hf, hb8, out);
    k_neg     <<<dim3(BC, NVT), dim3(256), 0, stream>>>(hb8, ub8, partial);
    k_redfinal<<<dim3(BATCH / 64), dim3(1024), 0, stream>>>(y, hf, emb_u, partial, out);
}

// Round 11
// 128.427 us; speedup vs baseline: 1.6624x; 1.0214x over previous
//
#include <hip/hip_runtime.h>
#include <math.h>

#define VOCAB 50000
#define VPAD  50048      // padded vocab rows (zeroed): no guards in hot loop
#define EMB   100
#define BATCH 2048
#define CTX   10

#define NVT   391        // 128-wide vocab tiles (391*128 = 50048)
#define BC    8          // batch chunks; block covers 256 b in 4 subtiles of 64
#define PROWS (2 * NVT)  // partial rows: (vy, v-half) = 782
#define NMG   (VPAD / 16)   // 3128 16-row fragment groups
#define CVTB  (NMG / 4)     // 782 cvt blocks (4 mg each)
#define HBLK  (BATCH / 2)   // 1024 h blocks (2 b each)

#define LOG2E 1.44269504088896340736f

#if __has_builtin(__builtin_amdgcn_exp2f)
#define EXP2(x) __builtin_amdgcn_exp2f(x)
#else
#define EXP2(x) __expf((x) * 0.6931471805599453f)
#endif

// fp8 fragment order (K=128, lane L = q*16 + c16 holds k = q*32 + j, j=0..31):
//   ub8[(mg*64 + L)*32 + j]   mg = v>>4, c16 = v&15      (2 KB per 16 v-rows)
//   hb8[(bg*64 + L)*32 + j]   bg = b>>4, c16 = b&15      (2 KB per 16 b)
// -> every A/B fragment load is 64 lanes x 32 B CONTIGUOUS (2 KB).
// u is PRE-SCALED by log2(e): GEMM emits scores in the log2 domain, so the
// sigmoid epilogue needs only raw v_exp_f32 (2^x), no per-element multiply.

typedef __attribute__((ext_vector_type(8))) int   i32x8;
typedef __attribute__((ext_vector_type(4))) float f32x4;

// ---------------- prep: emb_u*log2e -> fp8 frag-order ub8 + h (fp32 + fp8 frag-order) ----------------
__global__ __launch_bounds__(256)
void k_prep(const float* __restrict__ u, unsigned char* __restrict__ ub8,
            const int* __restrict__ x, const float* __restrict__ emb_v,
            float* __restrict__ hf, unsigned char* __restrict__ hb8,
            float* __restrict__ out) {
    const int blk = blockIdx.x;
    const int t   = threadIdx.x;
    if (blk < CVTB) {
        // ---- cvt: 4 mg groups per block; thread t writes 32 contiguous bytes ----
        const int mgid = blk * 4 + (t >> 6);
        const int L    = t & 63;
        const int c16  = L & 15;
        const int q    = L >> 4;
        const int row  = mgid * 16 + c16;
        const int e0   = q * 32;
        i32x8 o = (i32x8)0;
        if (row < VOCAB) {
            if (q < 3) {             // cols e0..e0+31 all valid
                const float4* p = (const float4*)&u[row * EMB + e0];
#pragma unroll
                for (int j = 0; j < 8; ++j) {
                    const float4 v = p[j];
                    int wd = __builtin_amdgcn_cvt_pk_fp8_f32(v.x * LOG2E, v.y * LOG2E, 0, false);
                    wd     = __builtin_amdgcn_cvt_pk_fp8_f32(v.z * LOG2E, v.w * LOG2E, wd, true);
                    o[j] = wd;
                }
            } else {                 // q==3: cols 96..99 valid, 100..127 zero
                const float4 v = *(const float4*)&u[row * EMB + 96];
                int wd = __builtin_amdgcn_cvt_pk_fp8_f32(v.x * LOG2E, v.y * LOG2E, 0, false);
                wd     = __builtin_amdgcn_cvt_pk_fp8_f32(v.z * LOG2E, v.w * LOG2E, wd, true);
                o[0] = wd;
            }
        }
        *(i32x8*)&ub8[((size_t)mgid * 64 + L) * 32] = o;   // coalesced: offset == t*32
    } else {
        // ---- h: 2 b per block ----
        const int b = (blk - CVTB) * 2 + (t >> 7);
        const int e = t & 127;
        if (blk == CVTB && t == 0) out[0] = 0.0f;
        float s = 0.0f;
        if (e < EMB) {
#pragma unroll
            for (int c = 0; c < CTX; ++c) {
                const int idx = x[b * CTX + c];
                s += emb_v[idx * EMB + e];
            }
            s *= (1.0f / CTX);
            hf[b * EMB + e] = s;
        }
        const unsigned char f8 =
            (unsigned char)(__builtin_amdgcn_cvt_pk_fp8_f32(s, 0.0f, 0, false) & 0xFF);
        hb8[((b >> 4) * 64 + (e >> 5) * 16 + (b & 15)) * 32 + (e & 31)] = f8;
    }
}

// ---------------- fused MX-fp8 MFMA GEMM (K=128 per instr) + sigmoid row-sum ----------------
// A = u*log2e (m=v), B = h (n=b). D: col(lane&15)=b, row(q*4+reg)=v.
// Unit E8M0 scales. A-frags cached in 32 VGPRs; bf software-pipelined one subtile
// ahead so trans-heavy epilogue covers load latency. NO LDS, NO barriers, NO atomics.
__global__ __launch_bounds__(256, 4)
void k_neg(const unsigned char* __restrict__ hb8, const unsigned char* __restrict__ ub8,
           float* __restrict__ partial) {
    const int t   = threadIdx.x;
    const int w   = t >> 6;          // wave 0..3
    const int L   = t & 63;
    const int wvh = w & 1;           // v half: mg 0..3 or 4..7 of the 128-v tile
    const int wbh = w >> 1;          // b half within 64-b subtile
    const int vy  = blockIdx.y;

    // ---- A fragments: 4 x 32 B/lane, loaded once, reused all subtiles ----
    i32x8 af[4];
#pragma unroll
    for (int mi = 0; mi < 4; ++mi)
        af[mi] = *(const i32x8*)&ub8[(((size_t)vy * 8 + wvh * 4 + mi) * 64 + L) * 32];

    const int b0base = blockIdx.x * (BATCH / BC);   // 256 b per block
    const int prow   = (2 * vy + wvh) * BATCH;
    const int NT     = (BATCH / BC) / 64;           // 4 subtiles

    // ---- prefetch bt=0 b-fragments ----
    i32x8 bf[2];
#pragma unroll
    for (int ni = 0; ni < 2; ++ni)
        bf[ni] = *(const i32x8*)&hb8[((size_t)((b0base >> 4) + wbh * 2 + ni) * 64 + L) * 32];

#pragma unroll 1
    for (int bt = 0; bt < NT; ++bt) {
        const int b0 = b0base + bt * 64;

        f32x4 acc[4][2];
#pragma unroll
        for (int mi = 0; mi < 4; ++mi)
#pragma unroll
            for (int ni = 0; ni < 2; ++ni) acc[mi][ni] = (f32x4)(0.0f);

#pragma unroll
        for (int mi = 0; mi < 4; ++mi)
#pragma unroll
            for (int ni = 0; ni < 2; ++ni)
                acc[mi][ni] = __builtin_amdgcn_mfma_scale_f32_16x16x128_f8f6f4(
                    af[mi], bf[ni], acc[mi][ni],
                    0, 0,                 // cbsz=fp8(e4m3), blgp=fp8(e4m3)
                    0, 0x7F7F7F7F,        // scale_a: 2^0
                    0, 0x7F7F7F7F);       // scale_b: 2^0

        // ---- prefetch next subtile's bf (clamped index; overlaps epilogue) ----
        const int btn = (bt + 1 < NT) ? bt + 1 : bt;
        const int Bgn = (b0base + btn * 64) >> 4;
#pragma unroll
        for (int ni = 0; ni < 2; ++ni)
            bf[ni] = *(const i32x8*)&hb8[((size_t)(Bgn + wbh * 2 + ni) * 64 + L) * 32];

        // ---- epilogue: sum_v sigmoid(-score); scores in log2 domain -> raw exp2 ----
#pragma unroll
        for (int ni = 0; ni < 2; ++ni) {
            float p = 0.0f;
#pragma unroll
            for (int mi = 0; mi < 4; ++mi) {
                const float ea = EXP2(acc[mi][ni][0]);
                const float eb = EXP2(acc[mi][ni][1]);
                const float ec = EXP2(acc[mi][ni][2]);
                const float ed = EXP2(acc[mi][ni][3]);
                const float n1 = 2.0f + ea + eb;
                const float d1 = fmaf(ea, eb, n1 - 1.0f);
                const float n2 = 2.0f + ec + ed;
                const float d2 = fmaf(ec, ed, n2 - 1.0f);
                const float N  = fmaf(n1, d2, n2 * d1);
                p = fmaf(N, __builtin_amdgcn_rcpf(d1 * d2), p);
            }
            p += __shfl_down(p, 32);   // fold q
            p += __shfl_down(p, 16);
            if (L < 16)
                partial[prow + b0 + wbh * 32 + ni * 16 + L] = p;
        }
    }
}

// ---------------- reduce partial rows + pos term + mean ----------------
__global__ void k_redfinal(const int* __restrict__ y, const float* __restrict__ hf,
                           const float* __restrict__ u, const float* __restrict__ partial,
                           float* __restrict__ out) {
    const int t    = threadIdx.x;
    const int lane = t & 63;
    const int w    = t >> 6;          // 0..15
    const int b    = blockIdx.x * 64 + lane;
    float s = 0.0f;
    for (int r = w; r < PROWS; r += 16)
        s += partial[r * BATCH + b];  // coalesced across 64 lanes
    __shared__ float red[16][64];
    red[w][lane] = s;
    __syncthreads();
    if (w == 0) {
        float ns = -(float)(VPAD - VOCAB) * 0.5f;   // remove zero-pad rows (exact 0.5 each)
#pragma unroll
        for (int i = 0; i < 16; ++i) ns += red[i][lane];

        const int yi = y[b];
        const float4* hp = (const float4*)&hf[b * EMB];
        const float4* up = (const float4*)&u[yi * EMB];
        float dot = 0.0f;
#pragma unroll
        for (int qq = 0; qq < EMB / 4; ++qq) {
            const float4 a = hp[qq];
            const float4 c = up[qq];
            dot += a.x * c.x + a.y * c.y + a.z * c.z + a.w * c.w;
        }
        const float pos = fmaxf(-dot, 0.0f) + log1pf(__expf(-fabsf(dot)));  // softplus(-dot)
        float val = pos + logf(ns);
#pragma unroll
        for (int off = 32; off; off >>= 1) val += __shfl_down(val, off, 64);
        if (lane == 0) atomicAdd(out, val * (1.0f / BATCH));
    }
}

extern "C" void kernel_launch(void* const* d_in, const int* in_sizes, int n_in,
                              void* d_out, int out_size, void* d_ws, size_t ws_size,
                              hipStream_t stream) {
    const int*   x     = (const int*)d_in[0];
    const int*   y     = (const int*)d_in[1];
    const float* emb_v = (const float*)d_in[2];
    const float* emb_u = (const float*)d_in[3];
    float* out = (float*)d_out;

    // workspace carve (~14 MB), 32B-aligned sections
    float*         hf      = (float*)d_ws;                            // 2048*100 fp32
    float*         partial = hf + BATCH * EMB;                        // 782*2048 fp32
    unsigned char* hb8     = (unsigned char*)(partial + PROWS * BATCH);  // 128*2048 B
    unsigned char* ub8     = hb8 + (size_t)(BATCH / 16) * 2048;       // 3128*2048 B

    k_prep    <<<dim3(CVTB + HBLK), dim3(256), 0, stream>>>(emb_u, ub8, x, emb_v, hf, hb8, out);
    k_neg     <<<dim3(BC, NVT), dim3(256), 0, stream>>>(hb8, ub8, partial);
    k_redfinal<<<dim3(BATCH / 64), dim3(1024), 0, stream>>>(y, hf, emb_u, partial, out);
}